// Round 9
// baseline (192.601 us; speedup 1.0000x reference)
//
#include <hip/hip_runtime.h>

typedef unsigned short u16;
typedef unsigned int u32;

#define BATCH 2
#define TTEXT 2048
#define DIM 1024
#define TMED 8
#define MTOK 256
#define HEADS 16
#define DHEAD 64
#define INNER 1024
#define TM 2048            // TMED * MTOK
#define QSCALE 0.125f      // DHEAD^-0.5
#define QCHUNK 128         // queries per attention block (was 64)

typedef __attribute__((ext_vector_type(8))) short bf16x8;
typedef __attribute__((ext_vector_type(4))) float f32x4;

__device__ __forceinline__ float b2f(u16 u){
  union { float f; u32 i; } x; x.i = ((u32)u) << 16; return x.f;
}
__device__ __forceinline__ u16 f2b(float f){
  union { float f; u32 i; } x; x.f = f;
  u32 r = x.i + 0x7FFFu + ((x.i >> 16) & 1u);   // RNE
  return (u16)(r >> 16);
}

#define GLDS16(g, l) __builtin_amdgcn_global_load_lds( \
    (const __attribute__((address_space(1))) u32*)(g), \
    (__attribute__((address_space(3))) u32*)(l), 16, 0, 0)

// ---------------- fused preprocessing: scan + LN + media cvt + W transpose ----------------
__global__ __launch_bounds__(256) void prep_kernel(
    const unsigned char* __restrict__ raw, int* __restrict__ tt,
    const float* __restrict__ x, const float* __restrict__ gamma,
    const float* __restrict__ beta, u16* __restrict__ xn,
    const float* __restrict__ media, u16* __restrict__ medb,
    const float* __restrict__ Wq, const float* __restrict__ Wkv,
    const float* __restrict__ Wout, u16* __restrict__ Wqt,
    u16* __restrict__ Wkvt, u16* __restrict__ Woutt)
{
  __shared__ float smem[32 * 33];      // 4224 B, reused by every path
  int bid = blockIdx.x;
  int t = threadIdx.x;

  if (bid == 0){
    // ---- scan ----
    int* sd = (int*)smem;
    int c = 0;
    for (int i = t; i < 4096; i += 256) c += (raw[i] != 0);
    sd[t] = c; __syncthreads();
    for (int off = 128; off; off >>= 1){
      if (t < off) sd[t] += sd[t + off];
      __syncthreads();
    }
    int is_byte = (sd[0] >= 9);
    __syncthreads();
    const int* as_int = (const int*)raw;
    for (int b = 0; b < BATCH; b++){
      int inc[8]; int s = 0;
      #pragma unroll
      for (int k = 0; k < 8; k++){
        int i = b * TTEXT + t * 8 + k;
        int v = is_byte ? (raw[i] != 0) : (as_int[i] != 0);
        s += v; inc[k] = s;
      }
      sd[t] = s; __syncthreads();
      for (int off = 1; off < 256; off <<= 1){
        int v2 = (t >= off) ? sd[t - off] : 0;
        __syncthreads();
        sd[t] += v2;
        __syncthreads();
      }
      int excl = sd[t] - s;
      #pragma unroll
      for (int k = 0; k < 8; k++) tt[b * TTEXT + t * 8 + k] = excl + inc[k];
      __syncthreads();
    }
  } else if (bid <= 4096){
    // ---- LayerNorm ----
    int row = bid - 1;
    float* ps  = smem;
    float* pss = smem + 4;
    float4 v = *(const float4*)(x + (size_t)row * DIM + t * 4);
    float s  = v.x + v.y + v.z + v.w;
    float ss = v.x*v.x + v.y*v.y + v.z*v.z + v.w*v.w;
    #pragma unroll
    for (int off = 32; off; off >>= 1){ s += __shfl_xor(s, off); ss += __shfl_xor(ss, off); }
    int w = t >> 6;
    if ((t & 63) == 0){ ps[w] = s; pss[w] = ss; }
    __syncthreads();
    if (t == 0){
      float S = ps[0] + ps[1] + ps[2] + ps[3];
      float SS = pss[0] + pss[1] + pss[2] + pss[3];
      float mu = S * (1.f / DIM);
      float var = SS * (1.f / DIM) - mu * mu;
      smem[8] = mu; smem[9] = rsqrtf(var + 1e-5f);
    }
    __syncthreads();
    float mu = smem[8], rs = smem[9];
    float4 g  = *(const float4*)(gamma + t * 4);
    float4 be = *(const float4*)(beta + t * 4);
    ushort4 o;
    o.x = f2b((v.x - mu) * rs * g.x + be.x);
    o.y = f2b((v.y - mu) * rs * g.y + be.y);
    o.z = f2b((v.z - mu) * rs * g.z + be.z);
    o.w = f2b((v.w - mu) * rs * g.w + be.w);
    *(ushort4*)(xn + (size_t)row * DIM + t * 4) = o;
  } else if (bid <= 8192){
    // ---- media fp32 -> bf16 ----
    int i = (bid - 4097) * 1024 + t * 4;
    float4 v = *(const float4*)(media + i);
    ushort4 o;
    o.x = f2b(v.x); o.y = f2b(v.y); o.z = f2b(v.z); o.w = f2b(v.w);
    *(ushort4*)(medb + i) = o;
  } else {
    // ---- W transpose ----
    int tb = bid - 8193;
    int z = tb >> 10;
    int rem = tb & 1023;
    int by = rem >> 5;
    int bx = rem & 31;
    float (*tile)[33] = (float(*)[33])smem;
    const float* W; u16* Wt; int N;
    if (z == 0){ W = Wq;   Wt = Wqt;   N = 1024; }
    else if (z == 1){ W = Wout; Wt = Woutt; N = 1024; }
    else { W = Wkv; Wt = Wkvt; N = 2048; bx += (z - 2) * 32; }
    const int K = 1024;
    int tx = t & 31, ty = t >> 5;       // 32 x 8
    int n = bx * 32 + tx;
    #pragma unroll
    for (int i = 0; i < 32; i += 8)
      tile[ty + i][tx] = W[(size_t)(by * 32 + ty + i) * N + n];
    __syncthreads();
    int k2 = by * 32 + tx;
    #pragma unroll
    for (int i = 0; i < 32; i += 8)
      Wt[(size_t)(bx * 32 + ty + i) * K + k2] = f2b(tile[tx][ty + i]);
  }
}

// ================= BM=256 8-phase GEMM (counted vmcnt, ks-half staging) =================
// ROUND-7 VERIFIED VERSION (fine phases). Round-8's merged phases regressed (m196
// confirmed); reverted byte-exact. BN=256: vm 8/4/0; BN=128: vm 6/3/0.
template<int MODE, int BN>
__device__ __forceinline__ void gemm256_body(u16* lds, int m0, int n0,
    const u16* __restrict__ A, const u16* __restrict__ Bt,
    void* __restrict__ Cp, u16* __restrict__ C2p, int N){
  const int K = 1024;
  const int NT = 16;                    // K / 64
  constexpr int BCOL  = BN / 64;        // 16-col frags per wave: 4 or 2
  constexpr int GB    = BN / 128;       // GLDS/thread per B ks-half: 2 or 1
  constexpr int BSLOT = BN * 32;        // elems per B ks-slot
  int tid = threadIdx.x;
  int wave = tid >> 6, lane = tid & 63;
  int quad = lane >> 4, l16 = lane & 15;

  int wm = (wave & 1) * 128, wn = (wave >> 1) * (BN / 4);

  u16* ldsB = lds + 32768;              // A region: 4 slots x 8192 elems

  f32x4 acc[8][BCOL];
  #pragma unroll
  for (int i = 0; i < 8; i++)
    #pragma unroll
    for (int j = 0; j < BCOL; j++) acc[i][j] = (f32x4){0.f, 0.f, 0.f, 0.f};

  const u16 *agp[2], *bgp[GB];
  #pragma unroll
  for (int g = 0; g < 2; g++){
    int r = (wave * 2 + g) * 16 + (lane >> 2);            // A tile-local row
    int gs = ((lane & 3) - ((r >> 1) & 3)) & 3;           // inverse col swizzle
    agp[g] = A + (size_t)(m0 + r) * K + gs * 8;
  }
  #pragma unroll
  for (int g = 0; g < GB; g++){
    int r = (wave * GB + g) * 16 + (lane >> 2);           // B tile-local row
    int gs = ((lane & 3) - ((r >> 1) & 3)) & 3;
    bgp[g] = Bt + (size_t)(n0 + r) * K + gs * 8;
  }

  auto stageA = [&](int u, int ks){
    u16* d = lds + (((u & 1) << 1) | ks) * 8192 + wave * 1024;
    #pragma unroll
    for (int g = 0; g < 2; g++)
      GLDS16(agp[g] + u * 64 + ks * 32, d + g * 512);
  };
  auto stageB = [&](int u, int ks){
    u16* d = ldsB + (((u & 1) << 1) | ks) * BSLOT + wave * (GB * 512);
    #pragma unroll
    for (int g = 0; g < GB; g++)
      GLDS16(bgp[g] + u * 64 + ks * 32, d + g * 512);
  };

  int offA[8], offB[BCOL];
  #pragma unroll
  for (int i = 0; i < 8; i++){
    int r = wm + i * 16 + l16;
    int s = (quad + ((r >> 1) & 3)) & 3;
    offA[i] = r * 32 + s * 8;
  }
  #pragma unroll
  for (int j = 0; j < BCOL; j++){
    int r = wn + j * 16 + l16;
    int s = (quad + ((r >> 1) & 3)) & 3;
    offB[j] = r * 32 + s * 8;
  }

  bf16x8 bf[BCOL];
  auto phase = [&](const u16* Ah, const u16* Bh, int ihalf, bool loadB){
    if (loadB){
      #pragma unroll
      for (int j = 0; j < BCOL; j++) bf[j] = *(const bf16x8*)&Bh[offB[j]];
    }
    bf16x8 af[4];
    #pragma unroll
    for (int i = 0; i < 4; i++) af[i] = *(const bf16x8*)&Ah[offA[ihalf * 4 + i]];
    __builtin_amdgcn_s_barrier();
    asm volatile("s_waitcnt lgkmcnt(0)" ::: "memory");
    __builtin_amdgcn_sched_barrier(0);
    __builtin_amdgcn_s_setprio(1);
    #pragma unroll
    for (int i = 0; i < 4; i++)
      #pragma unroll
      for (int j = 0; j < BCOL; j++)
        acc[ihalf * 4 + i][j] =
          __builtin_amdgcn_mfma_f32_16x16x32_bf16(af[i], bf[j], acc[ihalf * 4 + i][j], 0, 0, 0);
    __builtin_amdgcn_s_setprio(0);
  };

  auto wait_vm1 = [&](){   // 2*(GA+GB)
    if constexpr (BN == 256) asm volatile("s_waitcnt vmcnt(8)" ::: "memory");
    else                     asm volatile("s_waitcnt vmcnt(6)" ::: "memory");
  };
  auto wait_vm2 = [&](){   // GA+GB
    if constexpr (BN == 256) asm volatile("s_waitcnt vmcnt(4)" ::: "memory");
    else                     asm volatile("s_waitcnt vmcnt(3)" ::: "memory");
  };

  stageA(0, 0); stageB(0, 0);
  stageA(0, 1); stageB(0, 1);
  stageA(1, 0); stageB(1, 0);

  #pragma unroll 1
  for (int t = 0; t < NT - 1; t++){
    int c = t & 1;
    const u16* Ak0 = lds  + ((c << 1) | 0) * 8192;
    const u16* Bk0 = ldsB + ((c << 1) | 0) * BSLOT;
    const u16* Ak1 = lds  + ((c << 1) | 1) * 8192;
    const u16* Bk1 = ldsB + ((c << 1) | 1) * BSLOT;

    wait_vm1();
    __builtin_amdgcn_s_barrier();
    __builtin_amdgcn_sched_barrier(0);

    stageA(t + 1, 1);
    phase(Ak0, Bk0, 0, true);
    __builtin_amdgcn_s_barrier();
    __builtin_amdgcn_sched_barrier(0);

    stageB(t + 1, 1);
    phase(Ak0, Bk0, 1, false);

    wait_vm1();
    __builtin_amdgcn_s_barrier();
    __builtin_amdgcn_sched_barrier(0);

    if (t + 2 < NT) stageA(t + 2, 0);
    phase(Ak1, Bk1, 0, true);
    __builtin_amdgcn_s_barrier();
    __builtin_amdgcn_sched_barrier(0);

    if (t + 2 < NT) stageB(t + 2, 0);
    phase(Ak1, Bk1, 1, false);
  }

  {
    const u16* Ak0 = lds  + ((1 << 1) | 0) * 8192;
    const u16* Bk0 = ldsB + ((1 << 1) | 0) * BSLOT;
    const u16* Ak1 = lds  + ((1 << 1) | 1) * 8192;
    const u16* Bk1 = ldsB + ((1 << 1) | 1) * BSLOT;

    wait_vm2();
    __builtin_amdgcn_s_barrier();
    __builtin_amdgcn_sched_barrier(0);
    phase(Ak0, Bk0, 0, true);
    __builtin_amdgcn_s_barrier();
    __builtin_amdgcn_sched_barrier(0);
    phase(Ak0, Bk0, 1, false);

    asm volatile("s_waitcnt vmcnt(0)" ::: "memory");
    __builtin_amdgcn_s_barrier();
    __builtin_amdgcn_sched_barrier(0);
    phase(Ak1, Bk1, 0, true);
    __builtin_amdgcn_s_barrier();
    __builtin_amdgcn_sched_barrier(0);
    phase(Ak1, Bk1, 1, false);
  }

  #pragma unroll
  for (int i = 0; i < 8; i++){
    #pragma unroll
    for (int j = 0; j < BCOL; j++){
      int rG = m0 + wm + i * 16 + quad * 4;      // + ii
      int cG = n0 + wn + j * 16 + l16;
      if (MODE == 0){
        u16* C = (u16*)Cp;
        #pragma unroll
        for (int ii = 0; ii < 4; ii++)
          C[(size_t)(rG + ii) * N + cG] = f2b(acc[i][j][ii]);
      } else if (MODE == 1){
        float* C = (float*)Cp;
        #pragma unroll
        for (int ii = 0; ii < 4; ii++)
          C[(size_t)(rG + ii) * N + cG] = acc[i][j][ii];
      } else {
        int bb = rG >> 11, jj = rG & 2047;       // 4-row groups never cross batch
        if (cG < INNER){
          int hh = cG >> 6, dd = cG & 63;
          u16* kp = (u16*)Cp + (((size_t)bb * HEADS + hh) * TM + jj) * DHEAD + dd;
          #pragma unroll
          for (int ii = 0; ii < 4; ii++)
            kp[(size_t)ii * DHEAD] = f2b(acc[i][j][ii]);
        } else {
          int cc = cG - INNER;
          int hh = cc >> 6, dd = cc & 63;
          u16* vp = C2p + (((size_t)bb * HEADS + hh) * DHEAD + dd) * TM + jj;
          ushort4 o;
          o.x = f2b(acc[i][j][0]); o.y = f2b(acc[i][j][1]);
          o.z = f2b(acc[i][j][2]); o.w = f2b(acc[i][j][3]);
          *(ushort4*)vp = o;
        }
      }
    }
  }
}

// fused Q-proj (64 blocks) + KV-proj (128 blocks), 512 threads, BN=256
__global__ __launch_bounds__(512, 1) void qkv_kernel(const u16* __restrict__ xn,
                                                     const u16* __restrict__ Wqt,
                                                     u16* __restrict__ qb,
                                                     const u16* __restrict__ medb,
                                                     const u16* __restrict__ Wkvt,
                                                     u16* __restrict__ kB,
                                                     u16* __restrict__ vT){
  __shared__ u16 lds[65536];           // 128 KiB
  int bid = blockIdx.x;
  if (bid < 64){
    int xcd = bid & 7, idx = bid >> 3;
    gemm256_body<0, 256>(lds, (xcd * 2 + (idx & 1)) * 256, (idx >> 1) * 256,
                         xn, Wqt, qb, nullptr, 1024);
  } else {
    int b2 = bid - 64;
    int xcd = b2 & 7, idx = b2 >> 3;
    gemm256_body<2, 256>(lds, (xcd * 2 + (idx & 1)) * 256, (idx >> 1) * 256,
                         medb, Wkvt, kB, vT, 2048);
  }
}

// ---------------- output projection: 8-phase BM=256 BN=128, 128 blocks ----------------
__global__ __launch_bounds__(512, 1) void out_kernel(const u16* __restrict__ ao,
                                                     const u16* __restrict__ Woutt,
                                                     float* __restrict__ out){
  __shared__ u16 lds[49152];           // A 64 KiB + B 32 KiB
  int bid = blockIdx.x;
  int xcd = bid & 7, idx = bid >> 3;
  gemm256_body<1, 128>(lds, (xcd * 2 + (idx & 1)) * 256, (idx >> 1) * 128,
                       ao, Woutt, out, nullptr, 1024);
}

// ---------------- MFMA attention: 128 queries x 1 head per block ----------------
// QCHUNK 64 -> 128 (512 thr, 8 waves): avg present-media per chunk 2x1.25 -> 1.5,
// so K/V staging traffic drops ~40% and block count halves. Per-wave math is
// byte-identical to the verified 4-wave kernel (each wave owns 16 q-rows);
// __syncthreads fencing everywhere (no raw barriers).
__global__ __launch_bounds__(512, 2) void attn_kernel(const u16* __restrict__ qb,
                                                      const u16* __restrict__ kB,
                                                      const u16* __restrict__ vT,
                                                      const int* __restrict__ tt,
                                                      u16* __restrict__ ao){
  __shared__ u16 KsP[128 * 136];       // K half [128 keys][72] / P [128 q][136] / O strip [128 q][72]
  __shared__ u16 Vh[64 * 136];         // V half [64 d][128 keys pad->136]
  __shared__ int miq[QCHUNK];
  __shared__ int present[8];

  int t = threadIdx.x;
  int wave = t >> 6, lane = t & 63, quad = lane >> 4, l16 = lane & 15;
  int id = blockIdx.x;
  int pair = id & 31, chunk = id >> 5;  // XCD swizzle: id%8 fixed per (b,h)
  int b = pair >> 4, h = pair & 15;
  int q0 = chunk * QCHUNK;

  if (t < 8) present[t] = 0;
  __syncthreads();
  if (t < QCHUNK){
    int v = tt[b * TTEXT + q0 + t] - 1;
    miq[t] = v;
    if (v >= 0 && v < 8) present[v] = 1;
  }
  const u16* qrow = qb + (size_t)(b * TTEXT + q0 + wave * 16 + l16) * INNER
                       + h * DHEAD + quad * 8;
  bf16x8 aq0 = *(const bf16x8*)(qrow);
  bf16x8 aq1 = *(const bf16x8*)(qrow + 32);
  __syncthreads();                     // miq/present visible

  int myi[4];
  #pragma unroll
  for (int i = 0; i < 4; i++) myi[i] = miq[wave * 16 + quad * 4 + i];

  const size_t kvh = (size_t)b * HEADS + h;
  const u16* kg = kB + kvh * TM * DHEAD;            // [token][64]
  const u16* vg = vT + kvh * DHEAD * TM;            // [d][TM]

  f32x4 Osel[4];
  #pragma unroll
  for (int c4 = 0; c4 < 4; c4++) Osel[c4] = (f32x4){0.f, 0.f, 0.f, 0.f};

  for (int mi = 0; mi < 8; mi++){
    if (!present[mi]) continue;                     // block-uniform

    f32x4 S[16];
    #pragma unroll
    for (int c = 0; c < 16; c++) S[c] = (f32x4){0.f, 0.f, 0.f, 0.f};
    #pragma unroll
    for (int kh = 0; kh < 2; kh++){
      __syncthreads();   // prior KsP reads done (prev half QK / prev mi P/O)
      #pragma unroll
      for (int p = 0; p < 2; p++){
        int idx = p * 512 + t;
        int row = idx >> 3, seg = idx & 7;
        uint4 v = *(const uint4*)(kg + (size_t)(mi * MTOK + kh * 128 + row) * DHEAD + seg * 8);
        *(uint4*)(KsP + row * 72 + seg * 8) = v;
      }
      __syncthreads();
      #pragma unroll
      for (int ks = 0; ks < 2; ks++){
        bf16x8 aq = ks ? aq1 : aq0;
        #pragma unroll
        for (int c = 0; c < 8; c++){
          bf16x8 bk = *(const bf16x8*)&KsP[(c * 16 + l16) * 72 + ks * 32 + quad * 8];
          S[kh * 8 + c] = __builtin_amdgcn_mfma_f32_16x16x32_bf16(aq, bk, S[kh * 8 + c], 0, 0, 0);
        }
      }
    }

    float mx[4], sm[4];
    #pragma unroll
    for (int i = 0; i < 4; i++) mx[i] = -1e30f;
    #pragma unroll
    for (int c = 0; c < 16; c++)
      #pragma unroll
      for (int i = 0; i < 4; i++){
        float sv = S[c][i] * QSCALE; S[c][i] = sv; mx[i] = fmaxf(mx[i], sv);
      }
    #pragma unroll
    for (int off = 1; off < 16; off <<= 1)
      #pragma unroll
      for (int i = 0; i < 4; i++) mx[i] = fmaxf(mx[i], __shfl_xor(mx[i], off));
    #pragma unroll
    for (int i = 0; i < 4; i++) sm[i] = 0.f;
    #pragma unroll
    for (int c = 0; c < 16; c++)
      #pragma unroll
      for (int i = 0; i < 4; i++){
        float e = __expf(S[c][i] - mx[i]); S[c][i] = e; sm[i] += e;
      }
    #pragma unroll
    for (int off = 1; off < 16; off <<= 1)
      #pragma unroll
      for (int i = 0; i < 4; i++) sm[i] += __shfl_xor(sm[i], off);
    #pragma unroll
    for (int i = 0; i < 4; i++) sm[i] = 1.f / sm[i];

    f32x4 O[4];
    #pragma unroll
    for (int c4 = 0; c4 < 4; c4++) O[c4] = (f32x4){0.f, 0.f, 0.f, 0.f};
    #pragma unroll
    for (int kh = 0; kh < 2; kh++){
      __syncthreads();   // prior KsP/Vh reads done
      #pragma unroll
      for (int c = 0; c < 8; c++)
        #pragma unroll
        for (int i = 0; i < 4; i++)
          KsP[(wave * 16 + quad * 4 + i) * 136 + c * 16 + l16] = f2b(S[kh * 8 + c][i] * sm[i]);
      #pragma unroll
      for (int p = 0; p < 2; p++){
        int idx = p * 512 + t;
        int row = idx >> 4, seg = idx & 15;
        uint4 v = *(const uint4*)(vg + (size_t)row * TM + mi * MTOK + kh * 128 + seg * 8);
        *(uint4*)(Vh + row * 136 + seg * 8) = v;
      }
      __syncthreads();
      #pragma unroll
      for (int k0 = 0; k0 < 4; k0++){
        bf16x8 ap = *(const bf16x8*)&KsP[(wave * 16 + l16) * 136 + k0 * 32 + quad * 8];
        #pragma unroll
        for (int c4 = 0; c4 < 4; c4++){
          bf16x8 bv = *(const bf16x8*)&Vh[(c4 * 16 + l16) * 136 + k0 * 32 + quad * 8];
          O[c4] = __builtin_amdgcn_mfma_f32_16x16x32_bf16(ap, bv, O[c4], 0, 0, 0);
        }
      }
    }

    #pragma unroll
    for (int c4 = 0; c4 < 4; c4++)
      #pragma unroll
      for (int i = 0; i < 4; i++)
        Osel[c4][i] = (myi[i] == mi) ? O[c4][i] : Osel[c4][i];
  }

  __syncthreads();   // all waves' final P reads done before O-strip overwrite

  #pragma unroll
  for (int c4 = 0; c4 < 4; c4++)
    #pragma unroll
    for (int i = 0; i < 4; i++)
      KsP[(wave * 16 + quad * 4 + i) * 72 + c4 * 16 + l16] = f2b(Osel[c4][i]);
  int r = lane >> 2, sidx = lane & 3;
  #pragma unroll
  for (int p = 0; p < 2; p++){
    int seg = p * 4 + sidx;
    uint4 v = *(const uint4*)&KsP[(wave * 16 + r) * 72 + seg * 8];
    *(uint4*)(ao + (size_t)(b * TTEXT + q0 + wave * 16 + r) * INNER + h * DHEAD + seg * 8) = v;
  }
}

extern "C" void kernel_launch(void* const* d_in, const int* in_sizes, int n_in,
                              void* d_out, int out_size, void* d_ws, size_t ws_size,
                              hipStream_t stream){
  const float* x      = (const float*)d_in[0];
  const float* media  = (const float*)d_in[1];
  const unsigned char* locs = (const unsigned char*)d_in[2];
  const float* gamma  = (const float*)d_in[3];
  const float* beta   = (const float*)d_in[4];
  const float* Wq     = (const float*)d_in[5];
  const float* Wkv    = (const float*)d_in[6];
  const float* Wout   = (const float*)d_in[7];

  // workspace layout (~58 MB), all bf16 intermediates
  char* ws = (char*)d_ws;
  int* tt    = (int*)ws;   ws += 16384;
  u16* xn    = (u16*)ws;   ws += (size_t)4096 * 1024 * 2;   // [B*T][DIM]
  u16* medb  = (u16*)ws;   ws += (size_t)4096 * 1024 * 2;   // [B*TM][DIM]
  u16* Wqt   = (u16*)ws;   ws += (size_t)1024 * 1024 * 2;   // [INNER][DIM]
  u16* Wkvt  = (u16*)ws;   ws += (size_t)2048 * 1024 * 2;   // [2*INNER][DIM]
  u16* Woutt = (u16*)ws;   ws += (size_t)1024 * 1024 * 2;   // [DIM][INNER]
  u16* qb    = (u16*)ws;   ws += (size_t)4096 * 1024 * 2;   // [B*T][INNER]
  u16* kB    = (u16*)ws;   ws += (size_t)4096 * 1024 * 2;   // [B,H,TM,64] token-major
  u16* vT    = (u16*)ws;   ws += (size_t)4096 * 1024 * 2;   // [B,H,64,TM] dim-major
  u16* ao    = (u16*)ws;   ws += (size_t)4096 * 1024 * 2;   // [B*T][INNER]

  prep_kernel<<<12289, 256, 0, stream>>>(locs, tt, x, gamma, beta, xn,
                                         media, medb, Wq, Wkv, Wout,
                                         Wqt, Wkvt, Woutt);
  qkv_kernel<<<192, 512, 0, stream>>>(xn, Wqt, qb, medb, Wkvt, kB, vT);
  attn_kernel<<<dim3(512), 512, 0, stream>>>(qb, kB, vT, tt, ao);
  out_kernel<<<128, 512, 0, stream>>>(ao, Woutt, (float*)d_out);
}

// Round 10
// 182.083 us; speedup vs baseline: 1.0578x; 1.0578x over previous
//
#include <hip/hip_runtime.h>

typedef unsigned short u16;
typedef unsigned int u32;

#define BATCH 2
#define TTEXT 2048
#define DIM 1024
#define TMED 8
#define MTOK 256
#define HEADS 16
#define DHEAD 64
#define INNER 1024
#define TM 2048            // TMED * MTOK
#define QSCALE 0.125f      // DHEAD^-0.5
#define QCHUNK 64          // queries per attention block (reverted: 128 regressed, r9)

typedef __attribute__((ext_vector_type(8))) short bf16x8;
typedef __attribute__((ext_vector_type(4))) float f32x4;

__device__ __forceinline__ float b2f(u16 u){
  union { float f; u32 i; } x; x.i = ((u32)u) << 16; return x.f;
}
__device__ __forceinline__ u16 f2b(float f){
  union { float f; u32 i; } x; x.f = f;
  u32 r = x.i + 0x7FFFu + ((x.i >> 16) & 1u);   // RNE
  return (u16)(r >> 16);
}

#define GLDS16(g, l) __builtin_amdgcn_global_load_lds( \
    (const __attribute__((address_space(1))) u32*)(g), \
    (__attribute__((address_space(3))) u32*)(l), 16, 0, 0)

// ---------------- fused preprocessing: scan + LN + media cvt + W transpose ----------------
__global__ __launch_bounds__(256) void prep_kernel(
    const unsigned char* __restrict__ raw, int* __restrict__ tt,
    const float* __restrict__ x, const float* __restrict__ gamma,
    const float* __restrict__ beta, u16* __restrict__ xn,
    const float* __restrict__ media, u16* __restrict__ medb,
    const float* __restrict__ Wq, const float* __restrict__ Wkv,
    const float* __restrict__ Wout, u16* __restrict__ Wqt,
    u16* __restrict__ Wkvt, u16* __restrict__ Woutt)
{
  __shared__ float smem[32 * 33];      // 4224 B, reused by every path
  int bid = blockIdx.x;
  int t = threadIdx.x;

  if (bid == 0){
    // ---- scan ----
    int* sd = (int*)smem;
    int c = 0;
    for (int i = t; i < 4096; i += 256) c += (raw[i] != 0);
    sd[t] = c; __syncthreads();
    for (int off = 128; off; off >>= 1){
      if (t < off) sd[t] += sd[t + off];
      __syncthreads();
    }
    int is_byte = (sd[0] >= 9);
    __syncthreads();
    const int* as_int = (const int*)raw;
    for (int b = 0; b < BATCH; b++){
      int inc[8]; int s = 0;
      #pragma unroll
      for (int k = 0; k < 8; k++){
        int i = b * TTEXT + t * 8 + k;
        int v = is_byte ? (raw[i] != 0) : (as_int[i] != 0);
        s += v; inc[k] = s;
      }
      sd[t] = s; __syncthreads();
      for (int off = 1; off < 256; off <<= 1){
        int v2 = (t >= off) ? sd[t - off] : 0;
        __syncthreads();
        sd[t] += v2;
        __syncthreads();
      }
      int excl = sd[t] - s;
      #pragma unroll
      for (int k = 0; k < 8; k++) tt[b * TTEXT + t * 8 + k] = excl + inc[k];
      __syncthreads();
    }
  } else if (bid <= 4096){
    // ---- LayerNorm ----
    int row = bid - 1;
    float* ps  = smem;
    float* pss = smem + 4;
    float4 v = *(const float4*)(x + (size_t)row * DIM + t * 4);
    float s  = v.x + v.y + v.z + v.w;
    float ss = v.x*v.x + v.y*v.y + v.z*v.z + v.w*v.w;
    #pragma unroll
    for (int off = 32; off; off >>= 1){ s += __shfl_xor(s, off); ss += __shfl_xor(ss, off); }
    int w = t >> 6;
    if ((t & 63) == 0){ ps[w] = s; pss[w] = ss; }
    __syncthreads();
    if (t == 0){
      float S = ps[0] + ps[1] + ps[2] + ps[3];
      float SS = pss[0] + pss[1] + pss[2] + pss[3];
      float mu = S * (1.f / DIM);
      float var = SS * (1.f / DIM) - mu * mu;
      smem[8] = mu; smem[9] = rsqrtf(var + 1e-5f);
    }
    __syncthreads();
    float mu = smem[8], rs = smem[9];
    float4 g  = *(const float4*)(gamma + t * 4);
    float4 be = *(const float4*)(beta + t * 4);
    ushort4 o;
    o.x = f2b((v.x - mu) * rs * g.x + be.x);
    o.y = f2b((v.y - mu) * rs * g.y + be.y);
    o.z = f2b((v.z - mu) * rs * g.z + be.z);
    o.w = f2b((v.w - mu) * rs * g.w + be.w);
    *(ushort4*)(xn + (size_t)row * DIM + t * 4) = o;
  } else if (bid <= 8192){
    // ---- media fp32 -> bf16 ----
    int i = (bid - 4097) * 1024 + t * 4;
    float4 v = *(const float4*)(media + i);
    ushort4 o;
    o.x = f2b(v.x); o.y = f2b(v.y); o.z = f2b(v.z); o.w = f2b(v.w);
    *(ushort4*)(medb + i) = o;
  } else {
    // ---- W transpose ----
    int tb = bid - 8193;
    int z = tb >> 10;
    int rem = tb & 1023;
    int by = rem >> 5;
    int bx = rem & 31;
    float (*tile)[33] = (float(*)[33])smem;
    const float* W; u16* Wt; int N;
    if (z == 0){ W = Wq;   Wt = Wqt;   N = 1024; }
    else if (z == 1){ W = Wout; Wt = Woutt; N = 1024; }
    else { W = Wkv; Wt = Wkvt; N = 2048; bx += (z - 2) * 32; }
    const int K = 1024;
    int tx = t & 31, ty = t >> 5;       // 32 x 8
    int n = bx * 32 + tx;
    #pragma unroll
    for (int i = 0; i < 32; i += 8)
      tile[ty + i][tx] = W[(size_t)(by * 32 + ty + i) * N + n];
    __syncthreads();
    int k2 = by * 32 + tx;
    #pragma unroll
    for (int i = 0; i < 32; i += 8)
      Wt[(size_t)(bx * 32 + ty + i) * K + k2] = f2b(tile[tx][ty + i]);
  }
}

// ================= BM=256 8-phase GEMM (counted vmcnt, ks-half staging) =================
// ROUND-7 VERIFIED VERSION (fine phases). BN=256: vm 8/4/0; BN=128: vm 6/3/0.
template<int MODE, int BN>
__device__ __forceinline__ void gemm256_body(u16* lds, int m0, int n0,
    const u16* __restrict__ A, const u16* __restrict__ Bt,
    void* __restrict__ Cp, u16* __restrict__ C2p, int N){
  const int K = 1024;
  const int NT = 16;                    // K / 64
  constexpr int BCOL  = BN / 64;        // 16-col frags per wave: 4 or 2
  constexpr int GB    = BN / 128;       // GLDS/thread per B ks-half: 2 or 1
  constexpr int BSLOT = BN * 32;        // elems per B ks-slot
  int tid = threadIdx.x;
  int wave = tid >> 6, lane = tid & 63;
  int quad = lane >> 4, l16 = lane & 15;

  int wm = (wave & 1) * 128, wn = (wave >> 1) * (BN / 4);

  u16* ldsB = lds + 32768;              // A region: 4 slots x 8192 elems

  f32x4 acc[8][BCOL];
  #pragma unroll
  for (int i = 0; i < 8; i++)
    #pragma unroll
    for (int j = 0; j < BCOL; j++) acc[i][j] = (f32x4){0.f, 0.f, 0.f, 0.f};

  const u16 *agp[2], *bgp[GB];
  #pragma unroll
  for (int g = 0; g < 2; g++){
    int r = (wave * 2 + g) * 16 + (lane >> 2);            // A tile-local row
    int gs = ((lane & 3) - ((r >> 1) & 3)) & 3;           // inverse col swizzle
    agp[g] = A + (size_t)(m0 + r) * K + gs * 8;
  }
  #pragma unroll
  for (int g = 0; g < GB; g++){
    int r = (wave * GB + g) * 16 + (lane >> 2);           // B tile-local row
    int gs = ((lane & 3) - ((r >> 1) & 3)) & 3;
    bgp[g] = Bt + (size_t)(n0 + r) * K + gs * 8;
  }

  auto stageA = [&](int u, int ks){
    u16* d = lds + (((u & 1) << 1) | ks) * 8192 + wave * 1024;
    #pragma unroll
    for (int g = 0; g < 2; g++)
      GLDS16(agp[g] + u * 64 + ks * 32, d + g * 512);
  };
  auto stageB = [&](int u, int ks){
    u16* d = ldsB + (((u & 1) << 1) | ks) * BSLOT + wave * (GB * 512);
    #pragma unroll
    for (int g = 0; g < GB; g++)
      GLDS16(bgp[g] + u * 64 + ks * 32, d + g * 512);
  };

  int offA[8], offB[BCOL];
  #pragma unroll
  for (int i = 0; i < 8; i++){
    int r = wm + i * 16 + l16;
    int s = (quad + ((r >> 1) & 3)) & 3;
    offA[i] = r * 32 + s * 8;
  }
  #pragma unroll
  for (int j = 0; j < BCOL; j++){
    int r = wn + j * 16 + l16;
    int s = (quad + ((r >> 1) & 3)) & 3;
    offB[j] = r * 32 + s * 8;
  }

  bf16x8 bf[BCOL];
  auto phase = [&](const u16* Ah, const u16* Bh, int ihalf, bool loadB){
    if (loadB){
      #pragma unroll
      for (int j = 0; j < BCOL; j++) bf[j] = *(const bf16x8*)&Bh[offB[j]];
    }
    bf16x8 af[4];
    #pragma unroll
    for (int i = 0; i < 4; i++) af[i] = *(const bf16x8*)&Ah[offA[ihalf * 4 + i]];
    __builtin_amdgcn_s_barrier();
    asm volatile("s_waitcnt lgkmcnt(0)" ::: "memory");
    __builtin_amdgcn_sched_barrier(0);
    __builtin_amdgcn_s_setprio(1);
    #pragma unroll
    for (int i = 0; i < 4; i++)
      #pragma unroll
      for (int j = 0; j < BCOL; j++)
        acc[ihalf * 4 + i][j] =
          __builtin_amdgcn_mfma_f32_16x16x32_bf16(af[i], bf[j], acc[ihalf * 4 + i][j], 0, 0, 0);
    __builtin_amdgcn_s_setprio(0);
  };

  auto wait_vm1 = [&](){   // 2*(GA+GB)
    if constexpr (BN == 256) asm volatile("s_waitcnt vmcnt(8)" ::: "memory");
    else                     asm volatile("s_waitcnt vmcnt(6)" ::: "memory");
  };
  auto wait_vm2 = [&](){   // GA+GB
    if constexpr (BN == 256) asm volatile("s_waitcnt vmcnt(4)" ::: "memory");
    else                     asm volatile("s_waitcnt vmcnt(3)" ::: "memory");
  };

  stageA(0, 0); stageB(0, 0);
  stageA(0, 1); stageB(0, 1);
  stageA(1, 0); stageB(1, 0);

  #pragma unroll 1
  for (int t = 0; t < NT - 1; t++){
    int c = t & 1;
    const u16* Ak0 = lds  + ((c << 1) | 0) * 8192;
    const u16* Bk0 = ldsB + ((c << 1) | 0) * BSLOT;
    const u16* Ak1 = lds  + ((c << 1) | 1) * 8192;
    const u16* Bk1 = ldsB + ((c << 1) | 1) * BSLOT;

    wait_vm1();
    __builtin_amdgcn_s_barrier();
    __builtin_amdgcn_sched_barrier(0);

    stageA(t + 1, 1);
    phase(Ak0, Bk0, 0, true);
    __builtin_amdgcn_s_barrier();
    __builtin_amdgcn_sched_barrier(0);

    stageB(t + 1, 1);
    phase(Ak0, Bk0, 1, false);

    wait_vm1();
    __builtin_amdgcn_s_barrier();
    __builtin_amdgcn_sched_barrier(0);

    if (t + 2 < NT) stageA(t + 2, 0);
    phase(Ak1, Bk1, 0, true);
    __builtin_amdgcn_s_barrier();
    __builtin_amdgcn_sched_barrier(0);

    if (t + 2 < NT) stageB(t + 2, 0);
    phase(Ak1, Bk1, 1, false);
  }

  {
    const u16* Ak0 = lds  + ((1 << 1) | 0) * 8192;
    const u16* Bk0 = ldsB + ((1 << 1) | 0) * BSLOT;
    const u16* Ak1 = lds  + ((1 << 1) | 1) * 8192;
    const u16* Bk1 = ldsB + ((1 << 1) | 1) * BSLOT;

    wait_vm2();
    __builtin_amdgcn_s_barrier();
    __builtin_amdgcn_sched_barrier(0);
    phase(Ak0, Bk0, 0, true);
    __builtin_amdgcn_s_barrier();
    __builtin_amdgcn_sched_barrier(0);
    phase(Ak0, Bk0, 1, false);

    asm volatile("s_waitcnt vmcnt(0)" ::: "memory");
    __builtin_amdgcn_s_barrier();
    __builtin_amdgcn_sched_barrier(0);
    phase(Ak1, Bk1, 0, true);
    __builtin_amdgcn_s_barrier();
    __builtin_amdgcn_sched_barrier(0);
    phase(Ak1, Bk1, 1, false);
  }

  #pragma unroll
  for (int i = 0; i < 8; i++){
    #pragma unroll
    for (int j = 0; j < BCOL; j++){
      int rG = m0 + wm + i * 16 + quad * 4;      // + ii
      int cG = n0 + wn + j * 16 + l16;
      if (MODE == 0){
        u16* C = (u16*)Cp;
        #pragma unroll
        for (int ii = 0; ii < 4; ii++)
          C[(size_t)(rG + ii) * N + cG] = f2b(acc[i][j][ii]);
      } else if (MODE == 1){
        float* C = (float*)Cp;
        #pragma unroll
        for (int ii = 0; ii < 4; ii++)
          C[(size_t)(rG + ii) * N + cG] = acc[i][j][ii];
      } else {
        int bb = rG >> 11, jj = rG & 2047;       // 4-row groups never cross batch
        if (cG < INNER){
          int hh = cG >> 6, dd = cG & 63;
          u16* kp = (u16*)Cp + (((size_t)bb * HEADS + hh) * TM + jj) * DHEAD + dd;
          #pragma unroll
          for (int ii = 0; ii < 4; ii++)
            kp[(size_t)ii * DHEAD] = f2b(acc[i][j][ii]);
        } else {
          int cc = cG - INNER;
          int hh = cc >> 6, dd = cc & 63;
          u16* vp = C2p + (((size_t)bb * HEADS + hh) * DHEAD + dd) * TM + jj;
          ushort4 o;
          o.x = f2b(acc[i][j][0]); o.y = f2b(acc[i][j][1]);
          o.z = f2b(acc[i][j][2]); o.w = f2b(acc[i][j][3]);
          *(ushort4*)vp = o;
        }
      }
    }
  }
}

// fused Q-proj (64 blocks) + KV-proj (128 blocks), 512 threads, BN=256
__global__ __launch_bounds__(512, 1) void qkv_kernel(const u16* __restrict__ xn,
                                                     const u16* __restrict__ Wqt,
                                                     u16* __restrict__ qb,
                                                     const u16* __restrict__ medb,
                                                     const u16* __restrict__ Wkvt,
                                                     u16* __restrict__ kB,
                                                     u16* __restrict__ vT){
  __shared__ u16 lds[65536];           // 128 KiB
  int bid = blockIdx.x;
  if (bid < 64){
    int xcd = bid & 7, idx = bid >> 3;
    gemm256_body<0, 256>(lds, (xcd * 2 + (idx & 1)) * 256, (idx >> 1) * 256,
                         xn, Wqt, qb, nullptr, 1024);
  } else {
    int b2 = bid - 64;
    int xcd = b2 & 7, idx = b2 >> 3;
    gemm256_body<2, 256>(lds, (xcd * 2 + (idx & 1)) * 256, (idx >> 1) * 256,
                         medb, Wkvt, kB, vT, 2048);
  }
}

// ---------------- output projection: 8-phase BM=256 BN=128, 128 blocks ----------------
__global__ __launch_bounds__(512, 1) void out_kernel(const u16* __restrict__ ao,
                                                     const u16* __restrict__ Woutt,
                                                     float* __restrict__ out){
  __shared__ u16 lds[49152];           // A 64 KiB + B 32 KiB
  int bid = blockIdx.x;
  int xcd = bid & 7, idx = bid >> 3;
  gemm256_body<1, 128>(lds, (xcd * 2 + (idx & 1)) * 256, (idx >> 1) * 128,
                       ao, Woutt, out, nullptr, 1024);
}

// ---------------- MFMA attention: 64 queries x 1 head per block ----------------
// Verified round-6/7 version (QCHUNK=64, 256 thr, 4 waves, 1024 blocks, 3 blk/CU).
// Round-9's QCHUNK=128 regressed (−TLP for staging hiding); reverted byte-exact.
__global__ __launch_bounds__(256, 3) void attn_kernel(const u16* __restrict__ qb,
                                                      const u16* __restrict__ kB,
                                                      const u16* __restrict__ vT,
                                                      const int* __restrict__ tt,
                                                      u16* __restrict__ ao){
  __shared__ u16 KsP[128 * 72];
  __shared__ u16 Vh[64 * 136];
  __shared__ int miq[QCHUNK];
  __shared__ int present[8];

  int t = threadIdx.x;
  int wave = t >> 6, lane = t & 63, quad = lane >> 4, l16 = lane & 15;
  int id = blockIdx.x;
  int pair = id & 31, chunk = id >> 5;  // XCD swizzle: id%8 fixed per (b,h)
  int b = pair >> 4, h = pair & 15;
  int q0 = chunk * QCHUNK;

  if (t < 8) present[t] = 0;
  __syncthreads();
  if (t < QCHUNK){
    int v = tt[b * TTEXT + q0 + t] - 1;
    miq[t] = v;
    if (v >= 0 && v < 8) present[v] = 1;
  }
  const u16* qrow = qb + (size_t)(b * TTEXT + q0 + wave * 16 + l16) * INNER
                       + h * DHEAD + quad * 8;
  bf16x8 aq0 = *(const bf16x8*)(qrow);
  bf16x8 aq1 = *(const bf16x8*)(qrow + 32);
  __syncthreads();

  int myi[4];
  #pragma unroll
  for (int i = 0; i < 4; i++) myi[i] = miq[wave * 16 + quad * 4 + i];

  const size_t kvh = (size_t)b * HEADS + h;
  const u16* kg = kB + kvh * TM * DHEAD;
  const u16* vg = vT + kvh * DHEAD * TM;

  f32x4 Osel[4];
  #pragma unroll
  for (int c4 = 0; c4 < 4; c4++) Osel[c4] = (f32x4){0.f, 0.f, 0.f, 0.f};

  for (int mi = 0; mi < 8; mi++){
    if (!present[mi]) continue;

    f32x4 S[16];
    #pragma unroll
    for (int c = 0; c < 16; c++) S[c] = (f32x4){0.f, 0.f, 0.f, 0.f};
    #pragma unroll
    for (int kh = 0; kh < 2; kh++){
      __syncthreads();
      #pragma unroll
      for (int p = 0; p < 4; p++){
        int idx = p * 256 + t;
        int row = idx >> 3, seg = idx & 7;
        uint4 v = *(const uint4*)(kg + (size_t)(mi * MTOK + kh * 128 + row) * DHEAD + seg * 8);
        *(uint4*)(KsP + row * 72 + seg * 8) = v;
      }
      __syncthreads();
      #pragma unroll
      for (int ks = 0; ks < 2; ks++){
        bf16x8 aq = ks ? aq1 : aq0;
        #pragma unroll
        for (int c = 0; c < 8; c++){
          bf16x8 bk = *(const bf16x8*)&KsP[(c * 16 + l16) * 72 + ks * 32 + quad * 8];
          S[kh * 8 + c] = __builtin_amdgcn_mfma_f32_16x16x32_bf16(aq, bk, S[kh * 8 + c], 0, 0, 0);
        }
      }
    }

    float mx[4], sm[4];
    #pragma unroll
    for (int i = 0; i < 4; i++) mx[i] = -1e30f;
    #pragma unroll
    for (int c = 0; c < 16; c++)
      #pragma unroll
      for (int i = 0; i < 4; i++){
        float sv = S[c][i] * QSCALE; S[c][i] = sv; mx[i] = fmaxf(mx[i], sv);
      }
    #pragma unroll
    for (int off = 1; off < 16; off <<= 1)
      #pragma unroll
      for (int i = 0; i < 4; i++) mx[i] = fmaxf(mx[i], __shfl_xor(mx[i], off));
    #pragma unroll
    for (int i = 0; i < 4; i++) sm[i] = 0.f;
    #pragma unroll
    for (int c = 0; c < 16; c++)
      #pragma unroll
      for (int i = 0; i < 4; i++){
        float e = __expf(S[c][i] - mx[i]); S[c][i] = e; sm[i] += e;
      }
    #pragma unroll
    for (int off = 1; off < 16; off <<= 1)
      #pragma unroll
      for (int i = 0; i < 4; i++) sm[i] += __shfl_xor(sm[i], off);
    #pragma unroll
    for (int i = 0; i < 4; i++) sm[i] = 1.f / sm[i];

    f32x4 O[4];
    #pragma unroll
    for (int c4 = 0; c4 < 4; c4++) O[c4] = (f32x4){0.f, 0.f, 0.f, 0.f};
    #pragma unroll
    for (int kh = 0; kh < 2; kh++){
      __syncthreads();
      #pragma unroll
      for (int c = 0; c < 8; c++)
        #pragma unroll
        for (int i = 0; i < 4; i++)
          KsP[(wave * 16 + quad * 4 + i) * 136 + c * 16 + l16] = f2b(S[kh * 8 + c][i] * sm[i]);
      #pragma unroll
      for (int p = 0; p < 4; p++){
        int idx = p * 256 + t;
        int row = idx >> 4, seg = idx & 15;
        uint4 v = *(const uint4*)(vg + (size_t)row * TM + mi * MTOK + kh * 128 + seg * 8);
        *(uint4*)(Vh + row * 136 + seg * 8) = v;
      }
      __syncthreads();
      #pragma unroll
      for (int k0 = 0; k0 < 4; k0++){
        bf16x8 ap = *(const bf16x8*)&KsP[(wave * 16 + l16) * 136 + k0 * 32 + quad * 8];
        #pragma unroll
        for (int c4 = 0; c4 < 4; c4++){
          bf16x8 bv = *(const bf16x8*)&Vh[(c4 * 16 + l16) * 136 + k0 * 32 + quad * 8];
          O[c4] = __builtin_amdgcn_mfma_f32_16x16x32_bf16(ap, bv, O[c4], 0, 0, 0);
        }
      }
    }

    #pragma unroll
    for (int c4 = 0; c4 < 4; c4++)
      #pragma unroll
      for (int i = 0; i < 4; i++)
        Osel[c4][i] = (myi[i] == mi) ? O[c4][i] : Osel[c4][i];
  }

  __syncthreads();   // all waves' final P reads done before O-strip overwrite

  #pragma unroll
  for (int c4 = 0; c4 < 4; c4++)
    #pragma unroll
    for (int i = 0; i < 4; i++)
      KsP[(wave * 16 + quad * 4 + i) * 72 + c4 * 16 + l16] = f2b(Osel[c4][i]);
  int r = lane >> 2, sidx = lane & 3;
  #pragma unroll
  for (int p = 0; p < 2; p++){
    int seg = p * 4 + sidx;
    uint4 v = *(const uint4*)&KsP[(wave * 16 + r) * 72 + seg * 8];
    *(uint4*)(ao + (size_t)(b * TTEXT + q0 + wave * 16 + r) * INNER + h * DHEAD + seg * 8) = v;
  }
}

extern "C" void kernel_launch(void* const* d_in, const int* in_sizes, int n_in,
                              void* d_out, int out_size, void* d_ws, size_t ws_size,
                              hipStream_t stream){
  const float* x      = (const float*)d_in[0];
  const float* media  = (const float*)d_in[1];
  const unsigned char* locs = (const unsigned char*)d_in[2];
  const float* gamma  = (const float*)d_in[3];
  const float* beta   = (const float*)d_in[4];
  const float* Wq     = (const float*)d_in[5];
  const float* Wkv    = (const float*)d_in[6];
  const float* Wout   = (const float*)d_in[7];

  // workspace layout (~58 MB), all bf16 intermediates
  char* ws = (char*)d_ws;
  int* tt    = (int*)ws;   ws += 16384;
  u16* xn    = (u16*)ws;   ws += (size_t)4096 * 1024 * 2;   // [B*T][DIM]
  u16* medb  = (u16*)ws;   ws += (size_t)4096 * 1024 * 2;   // [B*TM][DIM]
  u16* Wqt   = (u16*)ws;   ws += (size_t)1024 * 1024 * 2;   // [INNER][DIM]
  u16* Wkvt  = (u16*)ws;   ws += (size_t)2048 * 1024 * 2;   // [2*INNER][DIM]
  u16* Woutt = (u16*)ws;   ws += (size_t)1024 * 1024 * 2;   // [DIM][INNER]
  u16* qb    = (u16*)ws;   ws += (size_t)4096 * 1024 * 2;   // [B*T][INNER]
  u16* kB    = (u16*)ws;   ws += (size_t)4096 * 1024 * 2;   // [B,H,TM,64] token-major
  u16* vT    = (u16*)ws;   ws += (size_t)4096 * 1024 * 2;   // [B,H,64,TM] dim-major
  u16* ao    = (u16*)ws;   ws += (size_t)4096 * 1024 * 2;   // [B*T][INNER]

  prep_kernel<<<12289, 256, 0, stream>>>(locs, tt, x, gamma, beta, xn,
                                         media, medb, Wq, Wkv, Wout,
                                         Wqt, Wkvt, Woutt);
  qkv_kernel<<<192, 512, 0, stream>>>(xn, Wqt, qb, medb, Wkvt, kB, vT);
  attn_kernel<<<dim3(1024), 256, 0, stream>>>(qb, kB, vT, tt, ao);
  out_kernel<<<128, 512, 0, stream>>>(ao, Woutt, (float*)d_out);
}